// Round 5
// baseline (311.273 us; speedup 1.0000x reference)
//
#include <hip/hip_runtime.h>
#include <math.h>

namespace {

constexpr int H = 2048;
constexpr int W = 2048;
constexpr int HW = H * W;
constexpr float TANH_C  = 1.1486328125f;
constexpr float DEG2RAD = 0.017453292519943295f; // np.float32(pi/180)
constexpr float RT2H    = 0.70710678118654752f;  // sqrt(2)/2
constexpr float LOG2E   = 1.4426950408889634f;   // log2(e)
constexpr float TWOPI   = 6.283185307179586f;

// --- guarded HW-transcendental wrappers (single VALU op each) ---
__device__ __forceinline__ float fexp2(float x) {
#if __has_builtin(__builtin_amdgcn_exp2f)
    return __builtin_amdgcn_exp2f(x);          // v_exp_f32: 2^x
#else
    return __exp2f(x);
#endif
}
__device__ __forceinline__ float fcos_rev(float x) {  // cos(2*pi*x)
#if __has_builtin(__builtin_amdgcn_cosf)
    return __builtin_amdgcn_cosf(x);           // v_cos_f32: revolutions
#else
    return __cosf(x * TWOPI);
#endif
}
__device__ __forceinline__ float fsin_rev(float x) {  // sin(2*pi*x)
#if __has_builtin(__builtin_amdgcn_sinf)
    return __builtin_amdgcn_sinf(x);
#else
    return __sinf(x * TWOPI);
#endif
}
__device__ __forceinline__ float frcp(float x) {
#if __has_builtin(__builtin_amdgcn_rcpf)
    return __builtin_amdgcn_rcpf(x);           // v_rcp_f32
#else
    return 1.0f / x;
#endif
}

// ---------------------------------------------------------------------------
// K1: pure streaming pass. No LDS, no barriers. Writes the full output:
//   o0 = 0 (p_ignite default), o1 = keep (continue burning), o2 = new_burned.
// Heavy cells' o0/o1 are fixed up by K2 (stream-ordered after K1).
// ---------------------------------------------------------------------------
__global__ __launch_bounds__(256) void wildfire_dense(
    const float* __restrict__ rand_co,
    const int* __restrict__ burning, const int* __restrict__ burned,
    const float* __restrict__ s_pc,
    float* __restrict__ out)
{
    const int idx = ((int)blockIdx.x * 256 + (int)threadIdx.x) * 4;
    const int4   b4  = *reinterpret_cast<const int4*>(burning + idx);
    const int4   bd4 = *reinterpret_cast<const int4*>(burned + idx);
    const float4 rc4 = *reinterpret_cast<const float4*>(rand_co + idx);
    const float  p_cont = s_pc[0];

    const int   bn[4] = {b4.x, b4.y, b4.z, b4.w};
    const int   bd[4] = {bd4.x, bd4.y, bd4.z, bd4.w};
    const float rc[4] = {rc4.x, rc4.y, rc4.z, rc4.w};

    float4 o1, o2;
    float* o1p = &o1.x; float* o2p = &o2.x;
#pragma unroll
    for (int x = 0; x < 4; ++x) {
        const bool isb  = (bn[x] != 0);
        const bool keep = isb && (rc[x] < p_cont);
        o1p[x] = keep ? 1.f : 0.f;
        o2p[x] = ((bd[x] != 0) || (isb && !keep)) ? 1.f : 0.f;
    }
    *reinterpret_cast<float4*>(out + idx)          = make_float4(0.f, 0.f, 0.f, 0.f);
    *reinterpret_cast<float4*>(out + HW + idx)     = o1;
    *reinterpret_cast<float4*>(out + 2 * HW + idx) = o2;
}

// ---------------------------------------------------------------------------
// K2: sparse fixup. Stage burning halo, compact heavy cells (any burning
// neighbor, ~8.6%) into an LDS worklist, process densely, scatter-store:
//   out[gidx]    = p_ignite   (heavy cells only)
//   out[HW+gidx] = 1          (only when newly ignited; K1 value correct else)
// new_burned never depends on p_ignite -> untouched.
// ---------------------------------------------------------------------------
__global__ __launch_bounds__(256) void wildfire_heavy(
    const float* __restrict__ p_veg,  const float* __restrict__ p_den,
    const float* __restrict__ wind_v, const float* __restrict__ wind_d,
    const float* __restrict__ slope,
    const float* __restrict__ s_a,  const float* __restrict__ s_ph,
    const float* __restrict__ s_c1, const float* __restrict__ s_c2,
    const float* __restrict__ rand_ig,
    const int* __restrict__ burning, const int* __restrict__ burned,
    float* __restrict__ out)
{
    // sb[r][4+k] = burning(i+r-1, j0+k) for k in [-1, 1024]; float 0/1
    __shared__ __align__(16) float sb[3][1032];
    __shared__ unsigned short q[1024];
    __shared__ int qn;

    const int t  = (int)threadIdx.x;
    const int i  = (int)blockIdx.y;
    const int j0 = (int)blockIdx.x * 1024;
    const int rowbase = i * W + j0;

    if (t == 0) qn = 0;

    // ---- Phase A: vectorized halo staging (int4 -> float 0/1) ----
    for (int r = 0; r < 3; ++r) {
        const int ii = i + r - 1;
        const bool rowok = (ii >= 0) && (ii < H);
        int4 v = make_int4(0, 0, 0, 0);
        if (rowok)
            v = *reinterpret_cast<const int4*>(burning + ii * W + j0 + 4 * t);
        float4 f;
        f.x = v.x ? 1.f : 0.f;  f.y = v.y ? 1.f : 0.f;
        f.z = v.z ? 1.f : 0.f;  f.w = v.w ? 1.f : 0.f;
        *reinterpret_cast<float4*>(&sb[r][4 + 4 * t]) = f;   // 16B-aligned
        if (t == 0)
            sb[r][3] = (rowok && j0 > 0) ?
                       (burning[ii * W + j0 - 1] ? 1.f : 0.f) : 0.f;
        if (t == 1)
            sb[r][4 + 1024] = (rowok && j0 + 1024 < W) ?
                       (burning[ii * W + j0 + 1024] ? 1.f : 0.f) : 0.f;
    }
    __syncthreads();

    // ---- Phase B: activity detection + worklist push ----
    const int jb = t * 4;
    {
        const float4 a = *reinterpret_cast<const float4*>(&sb[0][4 + jb]);
        const float4 b = *reinterpret_cast<const float4*>(&sb[1][4 + jb]);
        const float4 c = *reinterpret_cast<const float4*>(&sb[2][4 + jb]);
        const float r0[6] = {sb[0][3 + jb], a.x, a.y, a.z, a.w, sb[0][8 + jb]};
        const float r1[6] = {sb[1][3 + jb], b.x, b.y, b.z, b.w, sb[1][8 + jb]};
        const float r2[6] = {sb[2][3 + jb], c.x, c.y, c.z, c.w, sb[2][8 + jb]};
#pragma unroll
        for (int x = 0; x < 4; ++x) {
            const float anyn = ((r0[x] + r0[x+1]) + (r0[x+2] + r1[x]))
                             + ((r1[x+2] + r2[x]) + (r2[x+1] + r2[x+2]));
            if (anyn != 0.f) {
                const int pos = atomicAdd(&qn, 1);
                q[pos] = (unsigned short)(jb + x);
            }
        }
    }
    __syncthreads();

    // ---- Phase C: dense heavy-cell processing + scattered fixup stores ----
    const int n = qn;
    const float a_  = s_a[0];
    const float p_h = s_ph[0];
    const float c1  = s_c1[0];
    const float c2  = s_c2[0];
    const float aslL = (a_ * DEG2RAD) * LOG2E;

    for (int k = t; k < n; k += 256) {
        const int cell = (int)q[k];
        const int c    = 4 + cell;
        const int gidx = rowbase + cell;

        // issue all gathers first so latency overlaps the math below
        const float pv  = p_veg[gidx];
        const float pd  = p_den[gidx];
        const float wv  = wind_v[gidx];
        const float wd  = wind_d[gidx];
        const float rig = rand_ig[gidx];
        const int   bn  = burned[gidx];
        float sl[9];
        __builtin_memcpy(sl, slope + (size_t)gidx * 9, 9 * sizeof(float));

        const float b0 = sb[0][c-1], b1 = sb[0][c], b2 = sb[0][c+1];
        const float b3 = sb[1][c-1], bcn = sb[1][c], b5 = sb[1][c+1];
        const float b6 = sb[2][c-1], b7 = sb[2][c], b8 = sb[2][c+1];
        const float cnt = ((b0 + b1) + (b2 + b3)) + ((b5 + b6) + (b7 + b8));

        // revolutions for HW sin/cos: wd/360
        const float wrev = wd * (1.f / 360.f);
        const float cw = fcos_rev(wrev);
        const float sw = fsin_rev(wrev);

        const float Lc2wv = (LOG2E * c2) * wv;
        const float cwv = Lc2wv * cw, swv = Lc2wv * sw;
        const float cwr = RT2H * cwv, swr = RT2H * swv;
        const float dpl = cwr + swr;   //  45 deg
        const float dmi = cwr - swr;   // 315 deg
        const float p_base = (p_h * (1.f + pv)) * (1.f + pd);
        const float Cz2 = (2.f * LOG2E * TANH_C) * p_base
                        * fexp2(LOG2E * (c1 * wv - c2 * wv));

#define NEIGHBOR(K, b, T, sv)                                            \
        const float q##K = fmaf(aslL, (sv), (T));                        \
        const float z##K = Cz2 * fexp2(q##K);                            \
        const float E##K = fexp2(z##K);                                  \
        const float d##K = fmaf((b), E##K, 1.f);

        NEIGHBOR(0, b0,  dmi, sl[0])   // 315
        NEIGHBOR(1, b1, -swv, sl[1])   // 270
        NEIGHBOR(2, b2, -dpl, sl[2])   // 225
        NEIGHBOR(3, b3,  cwv, sl[3])   //   0
        NEIGHBOR(5, b5, -cwv, sl[5])   // 180
        NEIGHBOR(6, b6,  dpl, sl[6])   //  45
        NEIGHBOR(7, b7,  swv, sl[7])   //  90
        NEIGHBOR(8, b8, -dmi, sl[8])   // 135
#undef NEIGHBOR
        const float den = ((d0 * d1) * (d2 * d3)) * ((d5 * d6) * (d7 * d8));
        const float num = fexp2(cnt);             // 2^(#burning nbrs), exact
        const float pig = fmaf(-num, frcp(den), 1.f);

        out[gidx] = pig;                          // p_ignite fixup
        const bool ni = (bcn == 0.f) && (bn == 0) && (rig < pig);
        if (ni) out[HW + gidx] = 1.f;             // newly ignited fixup
    }
}

} // namespace

extern "C" void kernel_launch(void* const* d_in, const int* in_sizes, int n_in,
                              void* d_out, int out_size, void* d_ws, size_t ws_size,
                              hipStream_t stream)
{
    (void)in_sizes; (void)n_in; (void)out_size; (void)d_ws; (void)ws_size;

    // K1: pure stream over all cells (4 cells/thread)
    {
        dim3 grid(HW / 1024, 1, 1);
        dim3 block(256, 1, 1);
        hipLaunchKernelGGL(wildfire_dense, grid, block, 0, stream,
            (const float*)d_in[11],               // rand_co
            (const int*)d_in[12],                 // burning
            (const int*)d_in[13],                 // burned
            (const float*)d_in[9],                // p_continue
            (float*)d_out);
    }
    // K2: sparse heavy-cell fixup (stream-ordered after K1)
    {
        dim3 grid(W / 1024, H, 1);
        dim3 block(256, 1, 1);
        hipLaunchKernelGGL(wildfire_heavy, grid, block, 0, stream,
            (const float*)d_in[0],  (const float*)d_in[1],
            (const float*)d_in[2],  (const float*)d_in[3],
            (const float*)d_in[4],
            (const float*)d_in[5],  (const float*)d_in[6],
            (const float*)d_in[7],  (const float*)d_in[8],
            (const float*)d_in[10],               // rand_ig
            (const int*)d_in[12],   (const int*)d_in[13],
            (float*)d_out);
    }
}

// Round 8
// 305.935 us; speedup vs baseline: 1.0174x; 1.0174x over previous
//
#include <hip/hip_runtime.h>
#include <math.h>

namespace {

constexpr int H = 2048;
constexpr int W = 2048;
constexpr int HW = H * W;
constexpr int TR = 8;                 // tile rows
constexpr int TC = 512;               // tile cols
constexpr int NTX = W / TC;           // 4 tile cols
constexpr int NTY = H / TR;           // 256 tile rows
constexpr int BPY = NTY / 8;          // 32 row-tiles per XCD band

constexpr float TANH_C  = 1.1486328125f;
constexpr float DEG2RAD = 0.017453292519943295f; // np.float32(pi/180)
constexpr float RT2H    = 0.70710678118654752f;  // sqrt(2)/2
constexpr float LOG2E   = 1.4426950408889634f;   // log2(e)
constexpr float TWOPI   = 6.283185307179586f;

// --- guarded HW-transcendental wrappers (single VALU op each) ---
__device__ __forceinline__ float fexp2(float x) {
#if __has_builtin(__builtin_amdgcn_exp2f)
    return __builtin_amdgcn_exp2f(x);          // v_exp_f32: 2^x
#else
    return __exp2f(x);
#endif
}
__device__ __forceinline__ float fcos_rev(float x) {  // cos(2*pi*x)
#if __has_builtin(__builtin_amdgcn_cosf)
    return __builtin_amdgcn_cosf(x);           // v_cos_f32: revolutions
#else
    return __cosf(x * TWOPI);
#endif
}
__device__ __forceinline__ float fsin_rev(float x) {  // sin(2*pi*x)
#if __has_builtin(__builtin_amdgcn_sinf)
    return __builtin_amdgcn_sinf(x);
#else
    return __sinf(x * TWOPI);
#endif
}
__device__ __forceinline__ float frcp(float x) {
#if __has_builtin(__builtin_amdgcn_rcpf)
    return __builtin_amdgcn_rcpf(x);           // v_rcp_f32
#else
    return 1.0f / x;
#endif
}

// out layout: [0,HW) p_ignite, [HW,2HW) new_burning (0/1), [2HW,3HW) new_burned
// One fused kernel. Block = 256 threads owns an 8-row x 512-col tile.
//   Phase A: stage burning halo (10 x 514) into LDS (int4 -> float 0/1).
//   Phase B+D: detect heavy cells -> LDS worklist; dense-finish all outputs
//              (p_ignite=0, new_burning=keep, new_burned) with float4 stores.
//   Phase C: process worklist densely; scatter-fix out[idx]=pig and, when
//            newly ignited, out[HW+idx]=1. Barrier between D and C orders the
//            same-address stores (vmcnt drained at barrier; same CU/L2).
// Grid is 2D (4, 256) matching the passing rounds; XCD band swizzle applied
// to blockIdx.y only: g -> o=(g&7)*32+(g>>3), bijective on [0,256). Each XCD
// owns a contiguous 256-image-row band (burning slice 2.1 MB, L2-resident).
__global__ __launch_bounds__(256) void wildfire_step(
    const float* __restrict__ p_veg,  const float* __restrict__ p_den,
    const float* __restrict__ wind_v, const float* __restrict__ wind_d,
    const float* __restrict__ slope,
    const float* __restrict__ s_a,  const float* __restrict__ s_ph,
    const float* __restrict__ s_c1, const float* __restrict__ s_c2,
    const float* __restrict__ s_pc,
    const float* __restrict__ rand_ig, const float* __restrict__ rand_co,
    const int* __restrict__ burning, const int* __restrict__ burned,
    float* __restrict__ out)
{
    // sb[r][4+c] = burning(i0-1+r, j0+c), c in [0,512); [3]/[516] = col halo
    __shared__ __align__(16) float sb[TR + 2][520];   // 20.8 KB
    __shared__ unsigned short q[TR * TC];             // 8 KB
    __shared__ int qn;

    const int t = (int)threadIdx.x;
    const int g  = (int)blockIdx.y;
    const int ty = (g & 7) * BPY + (g >> 3);   // bijective XCD band decode
    const int tx = (int)blockIdx.x;
    const int i0 = ty * TR;
    const int j0 = tx * TC;

    if (t == 0) qn = 0;

    // ---- Phase A: stage burning halo ----
    for (int p = t; p < (TR + 2) * (TC / 4); p += 256) {
        const int r  = p >> 7;                  // / 128
        const int gq = p & 127;
        const int ii = i0 - 1 + r;
        int4 v = make_int4(0, 0, 0, 0);
        if (ii >= 0 && ii < H)
            v = *reinterpret_cast<const int4*>(burning + ii * W + j0 + 4 * gq);
        float4 f;
        f.x = v.x ? 1.f : 0.f;  f.y = v.y ? 1.f : 0.f;
        f.z = v.z ? 1.f : 0.f;  f.w = v.w ? 1.f : 0.f;
        *reinterpret_cast<float4*>(&sb[r][4 + 4 * gq]) = f;   // aligned
    }
    if (t < TR + 2) {                                   // left col halo
        const int ii = i0 - 1 + t;
        sb[t][3] = (ii >= 0 && ii < H && j0 > 0)
                 ? (burning[ii * W + j0 - 1] ? 1.f : 0.f) : 0.f;
    } else if (t >= 64 && t < 64 + TR + 2) {            // right col halo
        const int r  = t - 64;
        const int ii = i0 - 1 + r;
        sb[r][4 + TC] = (ii >= 0 && ii < H && j0 + TC < W)
                 ? (burning[ii * W + j0 + TC] ? 1.f : 0.f) : 0.f;
    }
    __syncthreads();

    // ---- Phase B+D: detect + push worklist, dense finish all outputs ----
    const float p_cont = s_pc[0];
#pragma unroll
    for (int k = 0; k < 4; ++k) {
        const int p   = t + (k << 8);
        const int row = p >> 7;                 // 0..7
        const int jb  = (p & 127) * 4;          // col of first owned cell
        const float4 a = *reinterpret_cast<const float4*>(&sb[row][4 + jb]);
        const float4 b = *reinterpret_cast<const float4*>(&sb[row + 1][4 + jb]);
        const float4 c = *reinterpret_cast<const float4*>(&sb[row + 2][4 + jb]);
        const float r0[6] = {sb[row][3 + jb],     a.x, a.y, a.z, a.w, sb[row][8 + jb]};
        const float r1[6] = {sb[row + 1][3 + jb], b.x, b.y, b.z, b.w, sb[row + 1][8 + jb]};
        const float r2[6] = {sb[row + 2][3 + jb], c.x, c.y, c.z, c.w, sb[row + 2][8 + jb]};

        bool isb[4];
#pragma unroll
        for (int x = 0; x < 4; ++x) {
            const float anyn = ((r0[x] + r0[x+1]) + (r0[x+2] + r1[x]))
                             + ((r1[x+2] + r2[x]) + (r2[x+1] + r2[x+2]));
            isb[x] = (r1[x+1] != 0.f);
            if (anyn != 0.f) {
                const int pos = atomicAdd(&qn, 1);
                q[pos] = (unsigned short)(row * TC + jb + x);
            }
        }

        const int gidx = (i0 + row) * W + j0 + jb;      // 16B-aligned
        const int4 bd4 = *reinterpret_cast<const int4*>(burned + gidx);
        const int  bn[4] = {bd4.x, bd4.y, bd4.z, bd4.w};
        float rc[4] = {1.f, 1.f, 1.f, 1.f};
        if (isb[0] || isb[1] || isb[2] || isb[3]) {
            const float4 v = *reinterpret_cast<const float4*>(rand_co + gidx);
            rc[0] = v.x; rc[1] = v.y; rc[2] = v.z; rc[3] = v.w;
        }
        float4 o1, o2;
        float* o1p = &o1.x; float* o2p = &o2.x;
#pragma unroll
        for (int x = 0; x < 4; ++x) {
            const bool keep = isb[x] && (rc[x] < p_cont);
            o1p[x] = keep ? 1.f : 0.f;
            o2p[x] = ((bn[x] != 0) || (isb[x] && !keep)) ? 1.f : 0.f;
        }
        *reinterpret_cast<float4*>(out + gidx)          = make_float4(0.f, 0.f, 0.f, 0.f);
        *reinterpret_cast<float4*>(out + HW + gidx)     = o1;
        *reinterpret_cast<float4*>(out + 2 * HW + gidx) = o2;
    }
    __syncthreads();   // drains vmcnt: dense stores complete before fixups

    // ---- Phase C: dense heavy-cell processing + scattered fixup stores ----
    const int n = qn;
    const float a_  = s_a[0];
    const float p_h = s_ph[0];
    const float c1  = s_c1[0];
    const float c2  = s_c2[0];
    const float aslL = (a_ * DEG2RAD) * LOG2E;

    for (int k = t; k < n; k += 256) {
        const int cell = (int)q[k];
        const int row  = cell >> 9;             // / TC
        const int col  = cell & 511;
        const int gidx = (i0 + row) * W + j0 + col;

        // issue gathers first so latency overlaps the math below
        const float pv  = p_veg[gidx];
        const float pd  = p_den[gidx];
        const float wv  = wind_v[gidx];
        const float wd  = wind_d[gidx];
        const float rig = rand_ig[gidx];
        const int   bn  = burned[gidx];
        float sl[9];
        __builtin_memcpy(sl, slope + (size_t)gidx * 9, 9 * sizeof(float));

        const float b0 = sb[row][3+col],   b1 = sb[row][4+col],    b2 = sb[row][5+col];
        const float b3 = sb[row+1][3+col], bcn = sb[row+1][4+col], b5 = sb[row+1][5+col];
        const float b6 = sb[row+2][3+col], b7 = sb[row+2][4+col],  b8 = sb[row+2][5+col];
        const float cnt = ((b0 + b1) + (b2 + b3)) + ((b5 + b6) + (b7 + b8));

        // revolutions for HW sin/cos: wd/360
        const float wrev = wd * (1.f / 360.f);
        const float cw = fcos_rev(wrev);
        const float sw = fsin_rev(wrev);

        const float Lc2wv = (LOG2E * c2) * wv;
        const float cwv = Lc2wv * cw, swv = Lc2wv * sw;
        const float cwr = RT2H * cwv, swr = RT2H * swv;
        const float dpl = cwr + swr;   //  45 deg
        const float dmi = cwr - swr;   // 315 deg
        const float p_base = (p_h * (1.f + pv)) * (1.f + pd);
        const float Cz2 = (2.f * LOG2E * TANH_C) * p_base
                        * fexp2(LOG2E * (c1 * wv - c2 * wv));

#define NEIGHBOR(K, b, T, sv)                                            \
        const float q##K = fmaf(aslL, (sv), (T));                        \
        const float z##K = Cz2 * fexp2(q##K);                            \
        const float E##K = fexp2(z##K);                                  \
        const float d##K = fmaf((b), E##K, 1.f);

        NEIGHBOR(0, b0,  dmi, sl[0])   // 315
        NEIGHBOR(1, b1, -swv, sl[1])   // 270
        NEIGHBOR(2, b2, -dpl, sl[2])   // 225
        NEIGHBOR(3, b3,  cwv, sl[3])   //   0
        NEIGHBOR(5, b5, -cwv, sl[5])   // 180
        NEIGHBOR(6, b6,  dpl, sl[6])   //  45
        NEIGHBOR(7, b7,  swv, sl[7])   //  90
        NEIGHBOR(8, b8, -dmi, sl[8])   // 135
#undef NEIGHBOR
        const float den = ((d0 * d1) * (d2 * d3)) * ((d5 * d6) * (d7 * d8));
        const float num = fexp2(cnt);             // 2^(#burning nbrs), exact
        const float pig = fmaf(-num, frcp(den), 1.f);

        out[gidx] = pig;                          // p_ignite fixup
        const bool ni = (bcn == 0.f) && (bn == 0) && (rig < pig);
        if (ni) out[HW + gidx] = 1.f;             // newly-ignited fixup
    }
}

} // namespace

extern "C" void kernel_launch(void* const* d_in, const int* in_sizes, int n_in,
                              void* d_out, int out_size, void* d_ws, size_t ws_size,
                              hipStream_t stream)
{
    (void)in_sizes; (void)n_in; (void)out_size; (void)d_ws; (void)ws_size;
    dim3 grid(NTX, NTY, 1);
    dim3 block(256, 1, 1);
    hipLaunchKernelGGL(wildfire_step, grid, block, 0, stream,
        (const float*)d_in[0],  (const float*)d_in[1],
        (const float*)d_in[2],  (const float*)d_in[3],
        (const float*)d_in[4],
        (const float*)d_in[5],  (const float*)d_in[6],
        (const float*)d_in[7],  (const float*)d_in[8],
        (const float*)d_in[9],
        (const float*)d_in[10], (const float*)d_in[11],
        (const int*)d_in[12],   (const int*)d_in[13],
        (float*)d_out);
}